// Round 4
// baseline (1468.329 us; speedup 1.0000x reference)
//
#include <hip/hip_runtime.h>

#define NA 10000
#define NE 320000

typedef short short8 __attribute__((ext_vector_type(8)));
typedef float f32x4 __attribute__((ext_vector_type(4)));

__device__ __forceinline__ float silu_f(float v) { return v / (1.0f + __expf(-v)); }

__device__ __forceinline__ void split_bf16(float x, unsigned short& h, unsigned short& l)
{
    unsigned int u = __float_as_uint(x);
    h = (unsigned short)(u >> 16);                       // truncated hi
    float hf = __uint_as_float((unsigned int)h << 16);
    unsigned int ul = __float_as_uint(x - hf) + 0x8000u; // lo, round-ish
    l = (unsigned short)(ul >> 16);
}

// ---------------- init ----------------------------------------------------------
__global__ __launch_bounds__(256) void k_init(
    const int* __restrict__ Z, const int* __restrict__ idx_m,
    const float* __restrict__ emb, const float* __restrict__ e_field,
    float* __restrict__ q, float* __restrict__ mu,
    float* __restrict__ Eat, int* __restrict__ counts, int* __restrict__ cursor)
{
    int gid = blockIdx.x * 256 + threadIdx.x;
    if (gid < NA * 384) mu[gid] = 0.0f;
    if (gid < NA * 128) {
        int i = gid >> 7, f = gid & 127;
        q[gid] = emb[Z[i] * 128 + f];
    }
    if (gid < NA * 3) {
        int i = gid / 3, d = gid - i * 3;
        Eat[gid] = e_field[idx_m[i] * 3 + d];
    }
    if (gid < NA) { counts[gid] = 0; cursor[gid] = 0; }
}

// ---------------- histogram idx_i -----------------------------------------------
__global__ __launch_bounds__(256) void k_count(
    const int* __restrict__ idx_i, int* __restrict__ counts)
{
    int e = blockIdx.x * 256 + threadIdx.x;
    if (e < NE) atomicAdd(&counts[idx_i[e]], 1);
}

// ---------------- exclusive scan -------------------------------------------------
__global__ __launch_bounds__(256) void k_scan(const int* __restrict__ counts,
                                              int* __restrict__ rowptr)
{
    __shared__ int part[256];
    int tid = threadIdx.x;
    const int CH = (NA + 255) / 256;
    int base = tid * CH;
    int s = 0;
    for (int i2 = 0; i2 < CH; i2++) {
        int idx = base + i2;
        if (idx < NA) s += counts[idx];
    }
    part[tid] = s;
    __syncthreads();
    for (int ofs = 1; ofs < 256; ofs <<= 1) {
        int v = part[tid];
        int add = (tid >= ofs) ? part[tid - ofs] : 0;
        __syncthreads();
        part[tid] = v + add;
        __syncthreads();
    }
    int run = (tid > 0) ? part[tid - 1] : 0;
    for (int i2 = 0; i2 < CH; i2++) {
        int idx = base + i2;
        if (idx < NA) { rowptr[idx] = run; run += counts[idx]; }
        else if (idx == NA) rowptr[NA] = run;
    }
}

// ---------------- geometry + scatter into CSR order -----------------------------
__global__ __launch_bounds__(256) void k_geom_scatter(
    const float* __restrict__ r_ij, const int* __restrict__ idx_i,
    const int* __restrict__ idx_j, const int* __restrict__ rowptr,
    int* __restrict__ cursor, float* __restrict__ phi_s,
    float4* __restrict__ df_s, int* __restrict__ j_s)
{
    int e = blockIdx.x * 256 + threadIdx.x;
    if (e >= NE) return;
    float x = r_ij[e*3+0], y = r_ij[e*3+1], z = r_ij[e*3+2];
    float d = sqrtf(x*x + y*y + z*z);
    float inv = 1.0f / d;
    float fc = (d < 5.0f) ? 0.5f * (__cosf(d * 0.628318530717958648f) + 1.0f) : 0.0f;
    int i = idx_i[e];
    int pos = rowptr[i] + atomicAdd(&cursor[i], 1);
    float4 dv; dv.x = x*inv; dv.y = y*inv; dv.z = z*inv; dv.w = fc;
    df_s[pos] = dv;
    j_s[pos] = idx_j[e];
    const float invw = 19.0f / 5.0f;
    float ph[20];
    #pragma unroll
    for (int k = 0; k < 20; k++) {
        float off = (5.0f / 19.0f) * (float)k;
        float u = (d - off) * invw;
        ph[k] = __expf(-0.5f * u * u) * fc;
    }
    #pragma unroll
    for (int c = 0; c < 5; c++) {
        float4 pv; pv.x = ph[c*4]; pv.y = ph[c*4+1]; pv.z = ph[c*4+2]; pv.w = ph[c*4+3];
        *(float4*)(phi_s + (size_t)pos*20 + c*4) = pv;
    }
}

// ---------------- weight prep: transpose + hi/lo bf16 split ----------------------
// Out layout: WT[n*K + k], hi and lo planes. One block = one 64x64 tile.
struct WDesc { const float* src; unsigned short* dh; unsigned short* dl; int K; int N; };
struct WPack { WDesc w[24]; };

__global__ __launch_bounds__(256) void k_wprep(WPack P)
{
    WDesc d = P.w[blockIdx.y];
    int ntx = (d.N + 63) >> 6, nty = (d.K + 63) >> 6;
    if ((int)blockIdx.x >= ntx * nty) return;
    int tn0 = (blockIdx.x % ntx) * 64, tk0 = (blockIdx.x / ntx) * 64;
    __shared__ float Ts[64][65];
    int tid = threadIdx.x;
    #pragma unroll
    for (int s = 0; s < 16; s++) {
        int idx = s * 256 + tid;
        int kr = idx >> 6, nc = idx & 63;
        int k = tk0 + kr, n = tn0 + nc;
        Ts[kr][nc] = (k < d.K && n < d.N) ? d.src[(size_t)k * d.N + n] : 0.0f;
    }
    __syncthreads();
    #pragma unroll
    for (int s = 0; s < 16; s++) {
        int idx = s * 256 + tid;
        int nr = idx >> 6, kc = idx & 63;
        int n = tn0 + nr, k = tk0 + kc;
        if (n < d.N && k < d.K) {
            unsigned short h, l;
            split_bf16(Ts[kc][nr], h, l);
            d.dh[(size_t)n * d.K + k] = h;
            d.dl[(size_t)n * d.K + k] = l;
        }
    }
}

// ---------------- MFMA GEMM (bf16 split-3): C = act(A[M,K] @ W[K,N] + b) ---------
// Block tile 128x128, 4 waves in 2x2. A staged fp32 in LDS, split in-register.
// B fragments read directly from pre-split transposed WT (global, L2-resident).
// mfma_f32_16x16x32_bf16: A[m=lane&15][k=quad*8+j]; B[k=quad*8+j][n=lane&15];
// D row=quad*4+reg, col=lane&15 (m89/m120-verified layouts).
template<int ACT>
__global__ __launch_bounds__(256, 2) void k_gmm(
    const float* __restrict__ A,
    const unsigned short* __restrict__ WTh, const unsigned short* __restrict__ WTl,
    const float* __restrict__ bias, float* __restrict__ C,
    int M, int K, int N)
{
    __shared__ float As[128 * 36];
    int tid = threadIdx.x, lane = tid & 63, wv = tid >> 6;
    int i0 = blockIdx.x * 128, n0 = blockIdx.y * 128;
    int wm = (wv >> 1) * 64, wn = (wv & 1) * 64;
    int m16 = lane & 15, quad = lane >> 4;

    f32x4 acc[4][4];
    #pragma unroll
    for (int a = 0; a < 4; a++)
        #pragma unroll
        for (int b = 0; b < 4; b++) acc[a][b] = 0.0f;

    for (int k0 = 0; k0 < K; k0 += 32) {
        __syncthreads();
        #pragma unroll
        for (int s = 0; s < 4; s++) {
            int idx = s * 256 + tid;              // 0..1023
            int r = idx >> 3, c4 = (idx & 7) << 2;
            float4 v = {0.f, 0.f, 0.f, 0.f};
            if (i0 + r < M) v = *(const float4*)(A + (size_t)(i0 + r) * K + k0 + c4);
            *(float4*)(As + r * 36 + c4) = v;
        }
        __syncthreads();
        short8 bh[4], bl[4];
        #pragma unroll
        for (int tn = 0; tn < 4; tn++) {
            int n = n0 + wn + tn * 16 + m16;
            size_t base = (size_t)n * K + k0 + quad * 8;
            bh[tn] = *(const short8*)(WTh + base);
            bl[tn] = *(const short8*)(WTl + base);
        }
        #pragma unroll
        for (int tm = 0; tm < 4; tm++) {
            const float* ap = As + (wm + tm * 16 + m16) * 36 + quad * 8;
            short8 ah, al;
            #pragma unroll
            for (int j = 0; j < 8; j++) {
                unsigned short h, l;
                split_bf16(ap[j], h, l);
                ah[j] = (short)h; al[j] = (short)l;
            }
            #pragma unroll
            for (int tn = 0; tn < 4; tn++) {
                acc[tm][tn] = __builtin_amdgcn_mfma_f32_16x16x32_bf16(ah, bh[tn], acc[tm][tn], 0, 0, 0);
                acc[tm][tn] = __builtin_amdgcn_mfma_f32_16x16x32_bf16(ah, bl[tn], acc[tm][tn], 0, 0, 0);
                acc[tm][tn] = __builtin_amdgcn_mfma_f32_16x16x32_bf16(al, bh[tn], acc[tm][tn], 0, 0, 0);
            }
        }
    }
    #pragma unroll
    for (int tm = 0; tm < 4; tm++) {
        #pragma unroll
        for (int r = 0; r < 4; r++) {
            int row = i0 + wm + tm * 16 + quad * 4 + r;
            if (row < M) {
                #pragma unroll
                for (int tn = 0; tn < 4; tn++) {
                    int col = n0 + wn + tn * 16 + m16;
                    float v = acc[tm][tn][r] + (bias ? bias[col] : 0.0f);
                    if (ACT) v = silu_f(v);
                    C[(size_t)row * N + col] = v;
                }
            }
        }
    }
}

// ---------------- edge aggregation: atom-centric, feature-split, no atomics ----
__global__ __launch_bounds__(256, 3) void k_edge3(
    int t, const float* __restrict__ phi_s, const float4* __restrict__ df_s,
    const int* __restrict__ j_s, const int* __restrict__ rowptr,
    const float* __restrict__ x, const float* __restrict__ mu_in,
    const float* __restrict__ filt_W, const float* __restrict__ filt_b,
    float* __restrict__ q, float* __restrict__ mu_out)
{
    int lane = threadIdx.x & 63;
    int wv   = threadIdx.x >> 6;
    int ia   = blockIdx.x * 2 + (wv >> 1);
    int h    = wv & 1;
    int f    = lane + h * 64;

    float wreg[3][20];
    float b3[3];
    #pragma unroll
    for (int c = 0; c < 3; c++) {
        int col = t * 384 + (2*c + h) * 64 + lane;
        b3[c] = filt_b[col];
        #pragma unroll
        for (int k = 0; k < 20; k++)
            wreg[c][k] = filt_W[k * 1152 + col];
    }

    float accq = 0.0f, acc0 = 0.0f, acc1 = 0.0f, acc2 = 0.0f;
    int p0 = rowptr[ia], p1 = rowptr[ia + 1];
    int p = p0;
    for (; p + 2 <= p1; p += 2) {
        int j0 = j_s[p], j1 = j_s[p + 1];
        float4 d0 = df_s[p], d1 = df_s[p + 1];
        float dots0[3], dots1[3];
        #pragma unroll
        for (int c = 0; c < 3; c++) { dots0[c] = d0.w * b3[c]; dots1[c] = d1.w * b3[c]; }
        #pragma unroll
        for (int kq = 0; kq < 5; kq++) {
            float4 a0 = *(const float4*)(phi_s + (size_t)p * 20 + kq * 4);
            float4 a1 = *(const float4*)(phi_s + (size_t)(p + 1) * 20 + kq * 4);
            #pragma unroll
            for (int c = 0; c < 3; c++) {
                dots0[c] = fmaf(a0.x, wreg[c][kq*4+0], dots0[c]);
                dots0[c] = fmaf(a0.y, wreg[c][kq*4+1], dots0[c]);
                dots0[c] = fmaf(a0.z, wreg[c][kq*4+2], dots0[c]);
                dots0[c] = fmaf(a0.w, wreg[c][kq*4+3], dots0[c]);
                dots1[c] = fmaf(a1.x, wreg[c][kq*4+0], dots1[c]);
                dots1[c] = fmaf(a1.y, wreg[c][kq*4+1], dots1[c]);
                dots1[c] = fmaf(a1.z, wreg[c][kq*4+2], dots1[c]);
                dots1[c] = fmaf(a1.w, wreg[c][kq*4+3], dots1[c]);
            }
        }
        float xq0 = x[(size_t)j0*384 + h*64       + lane];
        float xr0 = x[(size_t)j0*384 + (2+h)*64   + lane];
        float xm0 = x[(size_t)j0*384 + (4+h)*64   + lane];
        float m00 = mu_in[((size_t)j0*3 + 0)*128 + f];
        float m01 = mu_in[((size_t)j0*3 + 1)*128 + f];
        float m02 = mu_in[((size_t)j0*3 + 2)*128 + f];
        float xq1 = x[(size_t)j1*384 + h*64       + lane];
        float xr1 = x[(size_t)j1*384 + (2+h)*64   + lane];
        float xm1 = x[(size_t)j1*384 + (4+h)*64   + lane];
        float m10 = mu_in[((size_t)j1*3 + 0)*128 + f];
        float m11 = mu_in[((size_t)j1*3 + 1)*128 + f];
        float m12 = mu_in[((size_t)j1*3 + 2)*128 + f];
        float xxq0 = dots0[0] * xq0, xxr0 = dots0[1] * xr0, xxm0 = dots0[2] * xm0;
        float xxq1 = dots1[0] * xq1, xxr1 = dots1[1] * xr1, xxm1 = dots1[2] * xm1;
        accq += xxq0 + xxq1;
        acc0 += xxr0*d0.x + xxm0*m00 + xxr1*d1.x + xxm1*m10;
        acc1 += xxr0*d0.y + xxm0*m01 + xxr1*d1.y + xxm1*m11;
        acc2 += xxr0*d0.z + xxm0*m02 + xxr1*d1.z + xxm1*m12;
    }
    if (p < p1) {
        int j0 = j_s[p];
        float4 d0 = df_s[p];
        float dots0[3];
        #pragma unroll
        for (int c = 0; c < 3; c++) dots0[c] = d0.w * b3[c];
        #pragma unroll
        for (int kq = 0; kq < 5; kq++) {
            float4 a0 = *(const float4*)(phi_s + (size_t)p * 20 + kq * 4);
            #pragma unroll
            for (int c = 0; c < 3; c++) {
                dots0[c] = fmaf(a0.x, wreg[c][kq*4+0], dots0[c]);
                dots0[c] = fmaf(a0.y, wreg[c][kq*4+1], dots0[c]);
                dots0[c] = fmaf(a0.z, wreg[c][kq*4+2], dots0[c]);
                dots0[c] = fmaf(a0.w, wreg[c][kq*4+3], dots0[c]);
            }
        }
        float xq0 = x[(size_t)j0*384 + h*64     + lane];
        float xr0 = x[(size_t)j0*384 + (2+h)*64 + lane];
        float xm0 = x[(size_t)j0*384 + (4+h)*64 + lane];
        float m00 = mu_in[((size_t)j0*3 + 0)*128 + f];
        float m01 = mu_in[((size_t)j0*3 + 1)*128 + f];
        float m02 = mu_in[((size_t)j0*3 + 2)*128 + f];
        float xxq0 = dots0[0] * xq0, xxr0 = dots0[1] * xr0, xxm0 = dots0[2] * xm0;
        accq += xxq0;
        acc0 += xxr0*d0.x + xxm0*m00;
        acc1 += xxr0*d0.y + xxm0*m01;
        acc2 += xxr0*d0.z + xxm0*m02;
    }
    q[(size_t)ia*128 + f] += accq;
    mu_out[((size_t)ia*3 + 0)*128 + f] = mu_in[((size_t)ia*3 + 0)*128 + f] + acc0;
    mu_out[((size_t)ia*3 + 1)*128 + f] = mu_in[((size_t)ia*3 + 1)*128 + f] + acc1;
    mu_out[((size_t)ia*3 + 2)*128 + f] = mu_in[((size_t)ia*3 + 2)*128 + f] + acc2;
}

// ---------------- field interaction elementwise update -------------------------
__global__ __launch_bounds__(256) void k_field(
    const float* __restrict__ a_s, const float* __restrict__ av,
    const float* __restrict__ Eat, float* __restrict__ mu)
{
    int gid = blockIdx.x * 256 + threadIdx.x;
    if (gid >= NA * 128) return;
    int i = gid >> 7, f = gid & 127;
    float E0 = Eat[i*3+0], E1 = Eat[i*3+1], E2 = Eat[i*3+2];
    float a0 = av[(i*3+0)*128+f], a1 = av[(i*3+1)*128+f], a2 = av[(i*3+2)*128+f];
    float dot = a0*E0 + a1*E1 + a2*E2;
    float s = a_s[gid];
    mu[(i*3+0)*128+f] += s*E0 - dot*a0;
    mu[(i*3+1)*128+f] += s*E1 - dot*a1;
    mu[(i*3+2)*128+f] += s*E2 - dot*a2;
}

// ---------------- mixing: mu_Vn and ctx = [q, mu_Vn] ---------------------------
__global__ __launch_bounds__(256) void k_mixnorm(
    const float* __restrict__ q, const float* __restrict__ mumix,
    float* __restrict__ ctx)
{
    int gid = blockIdx.x * 256 + threadIdx.x;
    if (gid >= NA * 128) return;
    int i = gid >> 7, f = gid & 127;
    float v0 = mumix[(i*3+0)*256+f], v1 = mumix[(i*3+1)*256+f], v2 = mumix[(i*3+2)*256+f];
    float vn = sqrtf(v0*v0 + v1*v1 + v2*v2 + 1e-8f);
    ctx[i*256 + f]       = q[gid];
    ctx[i*256 + 128 + f] = vn;
}

// ---------------- mixing final update ------------------------------------------
__global__ __launch_bounds__(256) void k_mixupd(
    const float* __restrict__ y, const float* __restrict__ mumix,
    float* __restrict__ q, float* __restrict__ mu)
{
    int gid = blockIdx.x * 256 + threadIdx.x;
    if (gid >= NA * 128) return;
    int i = gid >> 7, f = gid & 127;
    float yq  = y[i*384 + f];
    float ym  = y[i*384 + 128 + f];
    float yqm = y[i*384 + 256 + f];
    float sdot = 0.f;
    #pragma unroll
    for (int d = 0; d < 3; d++)
        sdot += mumix[(i*3+d)*256 + f] * mumix[(i*3+d)*256 + 128 + f];
    q[gid] += yq + yqm * sdot;
    #pragma unroll
    for (int d = 0; d < 3; d++)
        mu[(i*3+d)*128 + f] += ym * mumix[(i*3+d)*256 + 128 + f];
}

// ---------------- pack output [N,4,128] = [q, mu] -------------------------------
__global__ __launch_bounds__(256) void k_pack(
    const float* __restrict__ q, const float* __restrict__ mu,
    float* __restrict__ out)
{
    int gid = blockIdx.x * 256 + threadIdx.x;
    if (gid >= NA * 512) return;
    int i = gid >> 9, c = gid & 511;
    out[gid] = (c < 128) ? q[i*128 + c] : mu[i*384 + (c - 128)];
}

extern "C" void kernel_launch(void* const* d_in, const int* in_sizes, int n_in,
                              void* d_out, int out_size, void* d_ws, size_t ws_size,
                              hipStream_t stream)
{
    const int*   Z       = (const int*)d_in[0];
    const float* r_ij    = (const float*)d_in[1];
    const int*   idx_i   = (const int*)d_in[2];
    const int*   idx_j   = (const int*)d_in[3];
    const int*   idx_m   = (const int*)d_in[4];
    const float* e_field = (const float*)d_in[5];
    const float* emb     = (const float*)d_in[6];
    const float* filt_W  = (const float*)d_in[7];
    const float* filt_b  = (const float*)d_in[8];
    const float* iW1     = (const float*)d_in[9];
    const float* ib1     = (const float*)d_in[10];
    const float* iW2     = (const float*)d_in[11];
    const float* ib2     = (const float*)d_in[12];
    const float* sW1     = (const float*)d_in[13];
    const float* sb1     = (const float*)d_in[14];
    const float* sW2     = (const float*)d_in[15];
    const float* sb2     = (const float*)d_in[16];
    const float* vW      = (const float*)d_in[17];
    const float* mmW     = (const float*)d_in[18];
    const float* mW1     = (const float*)d_in[19];
    const float* mb1     = (const float*)d_in[20];
    const float* mW2     = (const float*)d_in[21];
    const float* mb2     = (const float*)d_in[22];
    float* out = (float*)d_out;

    float* base = (float*)d_ws;
    size_t off = 0;
    auto alloc = [&](size_t n) { float* p = base + off; off += (n + 255) & ~(size_t)255; return p; };
    float* q     = alloc((size_t)NA*128);
    float* mu_a  = alloc((size_t)NA*384);
    float* mu_b  = alloc((size_t)NA*384);
    float* h     = alloc((size_t)NA*128);
    float* a_s   = alloc((size_t)NA*128);
    float* s384  = alloc((size_t)NA*384);
    float* mumix = alloc((size_t)NA*768);
    float* ctx   = alloc((size_t)NA*256);
    float* Eat   = alloc((size_t)NA*3);
    float* phi_s = alloc((size_t)NE*20);
    float4* df_s = (float4*)alloc((size_t)NE*4);
    int* rowptr  = (int*)alloc(NA + 1);
    int* counts  = (int*)alloc(NA);
    int* cursor  = (int*)alloc(NA);
    int* j_s     = (int*)alloc(NE);
    // weight hi/lo planes: 229376 elems per t * 3 = 688128 ushorts each plane
    unsigned short* wth = (unsigned short*)alloc(344064 + 256);
    unsigned short* wtl = (unsigned short*)alloc(344064 + 256);
    (void)ws_size; (void)in_sizes; (void)n_in; (void)out_size;

    // --- weight prep descriptors (per t: iW1,iW2,sW1,sW2,vW,mmW,mW1,mW2) -------
    WPack P;
    size_t woff = 0;
    unsigned short* WH[3][8];
    unsigned short* WL[3][8];
    int nw = 0;
    auto reg = [&](const float* src, int K, int N, int t, int slot) {
        P.w[nw].src = src; P.w[nw].dh = wth + woff; P.w[nw].dl = wtl + woff;
        P.w[nw].K = K; P.w[nw].N = N;
        WH[t][slot] = wth + woff; WL[t][slot] = wtl + woff;
        woff += (size_t)K * N; nw++;
    };
    for (int t = 0; t < 3; t++) {
        reg(iW1 + t*128*128, 128, 128, t, 0);
        reg(iW2 + t*128*384, 128, 384, t, 1);
        reg(sW1 + t*128*128, 128, 128, t, 2);
        reg(sW2 + t*128*128, 128, 128, t, 3);
        reg(vW  + t*128*128, 128, 128, t, 4);
        reg(mmW + t*128*256, 128, 256, t, 5);
        reg(mW1 + t*256*128, 256, 128, t, 6);
        reg(mW2 + t*128*384, 128, 384, t, 7);
    }

    k_wprep       <<<dim3(12, 24),          256, 0, stream>>>(P);
    k_init        <<<(NA*384 + 255)/256,    256, 0, stream>>>(Z, idx_m, emb, e_field, q, mu_a, Eat, counts, cursor);
    k_count       <<<(NE + 255)/256,        256, 0, stream>>>(idx_i, counts);
    k_scan        <<<1,                     256, 0, stream>>>(counts, rowptr);
    k_geom_scatter<<<(NE + 255)/256,        256, 0, stream>>>(r_ij, idx_i, idx_j, rowptr, cursor,
                                                              phi_s, df_s, j_s);

    const int GM  = (NA + 127) / 128;       // 79
    const int GM3 = (NA*3 + 127) / 128;     // 235
    float* mu_cur = mu_a;
    float* mu_nxt = mu_b;
    for (int t = 0; t < 3; t++) {
        // Interaction MLP: x = silu(q@iW1+b1)@iW2+b2
        k_gmm<1><<<dim3(GM, 1),  256, 0, stream>>>(q, WH[t][0], WL[t][0], ib1 + t*128, h,    NA, 128, 128);
        k_gmm<0><<<dim3(GM, 3),  256, 0, stream>>>(h, WH[t][1], WL[t][1], ib2 + t*384, s384, NA, 128, 384);
        // edge message passing (owner-exclusive, no atomics)
        k_edge3<<<NA/2, 256, 0, stream>>>(t, phi_s, df_s, j_s, rowptr, s384,
                                          mu_cur, filt_W, filt_b, q, mu_nxt);
        { float* tmp = mu_cur; mu_cur = mu_nxt; mu_nxt = tmp; }
        // FieldInteraction
        k_gmm<1><<<dim3(GM, 1),  256, 0, stream>>>(q,      WH[t][2], WL[t][2], sb1 + t*128, h,    NA,   128, 128);
        k_gmm<0><<<dim3(GM, 1),  256, 0, stream>>>(h,      WH[t][3], WL[t][3], sb2 + t*128, a_s,  NA,   128, 128);
        k_gmm<0><<<dim3(GM3, 1), 256, 0, stream>>>(mu_cur, WH[t][4], WL[t][4], nullptr,     s384, NA*3, 128, 128);
        k_field<<<(NA*128 + 255)/256, 256, 0, stream>>>(a_s, s384, Eat, mu_cur);
        // Mixing
        k_gmm<0><<<dim3(GM3, 2), 256, 0, stream>>>(mu_cur, WH[t][5], WL[t][5], nullptr,     mumix, NA*3, 128, 256);
        k_mixnorm<<<(NA*128 + 255)/256, 256, 0, stream>>>(q, mumix, ctx);
        k_gmm<1><<<dim3(GM, 1),  256, 0, stream>>>(ctx,    WH[t][6], WL[t][6], mb1 + t*128, h,    NA, 256, 128);
        k_gmm<0><<<dim3(GM, 3),  256, 0, stream>>>(h,      WH[t][7], WL[t][7], mb2 + t*384, s384, NA, 128, 384);
        k_mixupd<<<(NA*128 + 255)/256, 256, 0, stream>>>(s384, mumix, q, mu_cur);
    }
    k_pack<<<(NA*512 + 255)/256, 256, 0, stream>>>(q, mu_cur, out);
}

// Round 5
// 1116.292 us; speedup vs baseline: 1.3154x; 1.3154x over previous
//
#include <hip/hip_runtime.h>

#define NA 10000
#define NE 320000

typedef short short8 __attribute__((ext_vector_type(8)));
typedef unsigned short us4 __attribute__((ext_vector_type(4)));
typedef float f32x4 __attribute__((ext_vector_type(4)));

__device__ __forceinline__ float silu_f(float v) { return v / (1.0f + __expf(-v)); }

__device__ __forceinline__ void split_bf16(float x, unsigned short& h, unsigned short& l)
{
    unsigned int u = __float_as_uint(x);
    h = (unsigned short)(u >> 16);                       // truncated hi
    float hf = __uint_as_float((unsigned int)h << 16);
    unsigned int ul = __float_as_uint(x - hf) + 0x8000u; // lo, round-ish
    l = (unsigned short)(ul >> 16);
}

// ---------------- init ----------------------------------------------------------
__global__ __launch_bounds__(256) void k_init(
    const int* __restrict__ Z, const int* __restrict__ idx_m,
    const float* __restrict__ emb, const float* __restrict__ e_field,
    float* __restrict__ q, float* __restrict__ mu,
    float* __restrict__ Eat, int* __restrict__ counts, int* __restrict__ cursor)
{
    int gid = blockIdx.x * 256 + threadIdx.x;
    if (gid < NA * 384) mu[gid] = 0.0f;
    if (gid < NA * 128) {
        int i = gid >> 7, f = gid & 127;
        q[gid] = emb[Z[i] * 128 + f];
    }
    if (gid < NA * 3) {
        int i = gid / 3, d = gid - i * 3;
        Eat[gid] = e_field[idx_m[i] * 3 + d];
    }
    if (gid < NA) { counts[gid] = 0; cursor[gid] = 0; }
}

// ---------------- histogram idx_i -----------------------------------------------
__global__ __launch_bounds__(256) void k_count(
    const int* __restrict__ idx_i, int* __restrict__ counts)
{
    int e = blockIdx.x * 256 + threadIdx.x;
    if (e < NE) atomicAdd(&counts[idx_i[e]], 1);
}

// ---------------- exclusive scan -------------------------------------------------
__global__ __launch_bounds__(256) void k_scan(const int* __restrict__ counts,
                                              int* __restrict__ rowptr)
{
    __shared__ int part[256];
    int tid = threadIdx.x;
    const int CH = (NA + 255) / 256;
    int base = tid * CH;
    int s = 0;
    for (int i2 = 0; i2 < CH; i2++) {
        int idx = base + i2;
        if (idx < NA) s += counts[idx];
    }
    part[tid] = s;
    __syncthreads();
    for (int ofs = 1; ofs < 256; ofs <<= 1) {
        int v = part[tid];
        int add = (tid >= ofs) ? part[tid - ofs] : 0;
        __syncthreads();
        part[tid] = v + add;
        __syncthreads();
    }
    int run = (tid > 0) ? part[tid - 1] : 0;
    for (int i2 = 0; i2 < CH; i2++) {
        int idx = base + i2;
        if (idx < NA) { rowptr[idx] = run; run += counts[idx]; }
        else if (idx == NA) rowptr[NA] = run;
    }
}

// ---------------- geometry + scatter into CSR order -----------------------------
__global__ __launch_bounds__(256) void k_geom_scatter(
    const float* __restrict__ r_ij, const int* __restrict__ idx_i,
    const int* __restrict__ idx_j, const int* __restrict__ rowptr,
    int* __restrict__ cursor, float* __restrict__ phi_s,
    float4* __restrict__ df_s, int* __restrict__ j_s)
{
    int e = blockIdx.x * 256 + threadIdx.x;
    if (e >= NE) return;
    float x = r_ij[e*3+0], y = r_ij[e*3+1], z = r_ij[e*3+2];
    float d = sqrtf(x*x + y*y + z*z);
    float inv = 1.0f / d;
    float fc = (d < 5.0f) ? 0.5f * (__cosf(d * 0.628318530717958648f) + 1.0f) : 0.0f;
    int i = idx_i[e];
    int pos = rowptr[i] + atomicAdd(&cursor[i], 1);
    float4 dv; dv.x = x*inv; dv.y = y*inv; dv.z = z*inv; dv.w = fc;
    df_s[pos] = dv;
    j_s[pos] = idx_j[e];
    const float invw = 19.0f / 5.0f;
    float ph[20];
    #pragma unroll
    for (int k = 0; k < 20; k++) {
        float off = (5.0f / 19.0f) * (float)k;
        float u = (d - off) * invw;
        ph[k] = __expf(-0.5f * u * u) * fc;
    }
    #pragma unroll
    for (int c = 0; c < 5; c++) {
        float4 pv; pv.x = ph[c*4]; pv.y = ph[c*4+1]; pv.z = ph[c*4+2]; pv.w = ph[c*4+3];
        *(float4*)(phi_s + (size_t)pos*20 + c*4) = pv;
    }
}

// ---------------- weight prep: hi/lo bf16 split into MFMA-fragment-linear order --
// Dest layout: for strip sIdx (16 cols), k-block kb (32 ks), lane (quad,m16):
//   dest[ ((sIdx*kBlks + kb)*64 + lane)*8 + j ] = W[kb*32+quad*8+j][sIdx*16+m16]
// so a wave's B-fragment load is one contiguous 1KB short8 read.
struct WDesc { const float* src; unsigned short* dh; unsigned short* dl; int K; int N; };
struct WPack { WDesc w[24]; };

__global__ __launch_bounds__(256) void k_wprep(WPack P)
{
    WDesc d = P.w[blockIdx.y];
    int kBlks = d.K >> 5, nStrips = d.N >> 4;
    int total = nStrips * kBlks * 64;
    int g = blockIdx.x * 256 + threadIdx.x;
    if (g >= total) return;
    int lane = g & 63, rem = g >> 6;
    int kb = rem % kBlks, sIdx = rem / kBlks;
    int m16 = lane & 15, quad = lane >> 4;
    int n = sIdx * 16 + m16;
    int kbase = kb * 32 + quad * 8;
    size_t dofs = (size_t)g * 8;
    #pragma unroll
    for (int jj = 0; jj < 8; jj++) {
        unsigned short h, l;
        split_bf16(d.src[(size_t)(kbase + jj) * d.N + n], h, l);
        d.dh[dofs + jj] = h;
        d.dl[dofs + jj] = l;
    }
}

// ---------------- MFMA GEMM (bf16 split-3): C = act(A[M,K] @ W[K,N] + b) ---------
// 64x64 tile, 4 waves = 4 n-strips of 16 cols. A staged hi/lo bf16 in LDS (split
// once at staging). B fragments are contiguous short8 reads from packed planes.
template<int ACT>
__global__ __launch_bounds__(256) void k_gmm2(
    const float* __restrict__ A,
    const unsigned short* __restrict__ Bh, const unsigned short* __restrict__ Bl,
    const float* __restrict__ bias, float* __restrict__ C,
    int M, int K, int N)
{
    __shared__ unsigned short Ahs[64 * 40];
    __shared__ unsigned short Als[64 * 40];
    int tid = threadIdx.x, lane = tid & 63, wv = tid >> 6;
    int i0 = blockIdx.x * 64, n0 = blockIdx.y * 64;
    int m16 = lane & 15, quad = lane >> 4;
    int kBlks = K >> 5;
    int sIdx = blockIdx.y * 4 + wv;

    f32x4 acc[4];
    #pragma unroll
    for (int a = 0; a < 4; a++) acc[a] = 0.0f;

    for (int kb = 0; kb < kBlks; kb++) {
        int k0 = kb << 5;
        __syncthreads();
        #pragma unroll
        for (int s = 0; s < 2; s++) {
            int idx = s * 256 + tid;          // 0..511
            int r = idx >> 3, c4 = (idx & 7) << 2;
            float4 v = {0.f, 0.f, 0.f, 0.f};
            if (i0 + r < M) v = *(const float4*)(A + (size_t)(i0 + r) * K + k0 + c4);
            unsigned short h0,l0,h1,l1,h2,l2,h3,l3;
            split_bf16(v.x, h0, l0); split_bf16(v.y, h1, l1);
            split_bf16(v.z, h2, l2); split_bf16(v.w, h3, l3);
            us4 hv = {h0, h1, h2, h3}, lv = {l0, l1, l2, l3};
            *(us4*)(Ahs + r * 40 + c4) = hv;
            *(us4*)(Als + r * 40 + c4) = lv;
        }
        __syncthreads();
        size_t bofs = (((size_t)sIdx * kBlks + kb) * 64 + lane) * 8;
        short8 bh = *(const short8*)(Bh + bofs);
        short8 bl = *(const short8*)(Bl + bofs);
        #pragma unroll
        for (int tm = 0; tm < 4; tm++) {
            short8 ah = *(const short8*)(Ahs + (tm * 16 + m16) * 40 + quad * 8);
            short8 al = *(const short8*)(Als + (tm * 16 + m16) * 40 + quad * 8);
            acc[tm] = __builtin_amdgcn_mfma_f32_16x16x32_bf16(ah, bh, acc[tm], 0, 0, 0);
            acc[tm] = __builtin_amdgcn_mfma_f32_16x16x32_bf16(ah, bl, acc[tm], 0, 0, 0);
            acc[tm] = __builtin_amdgcn_mfma_f32_16x16x32_bf16(al, bh, acc[tm], 0, 0, 0);
        }
    }
    int col = n0 + wv * 16 + m16;
    float bv = bias ? bias[col] : 0.0f;
    #pragma unroll
    for (int tm = 0; tm < 4; tm++) {
        #pragma unroll
        for (int r = 0; r < 4; r++) {
            int row = i0 + tm * 16 + quad * 4 + r;
            if (row < M) {
                float v = acc[tm][r] + bv;
                if (ACT) v = silu_f(v);
                C[(size_t)row * N + col] = v;
            }
        }
    }
}

// ---------------- edge aggregation: atom-centric, feature-split, 4-edge batch ---
// Block = 4 waves = 2 atoms x 2 feature-halves. Wave (ia,h) owns features
// f = lane + h*64, channels {h, 2+h, 4+h}. Filter weights in 60 VGPRs. No atomics.
__global__ __launch_bounds__(256, 3) void k_edge4(
    int t, const float* __restrict__ phi_s, const float4* __restrict__ df_s,
    const int* __restrict__ j_s, const int* __restrict__ rowptr,
    const float* __restrict__ x, const float* __restrict__ mu_in,
    const float* __restrict__ filt_W, const float* __restrict__ filt_b,
    float* __restrict__ q, float* __restrict__ mu_out)
{
    int lane = threadIdx.x & 63;
    int wv   = threadIdx.x >> 6;
    int ia   = blockIdx.x * 2 + (wv >> 1);
    int h    = wv & 1;
    int f    = lane + h * 64;

    float wreg[3][20];
    float b3[3];
    #pragma unroll
    for (int c = 0; c < 3; c++) {
        int col = t * 384 + (2*c + h) * 64 + lane;
        b3[c] = filt_b[col];
        #pragma unroll
        for (int k = 0; k < 20; k++)
            wreg[c][k] = filt_W[k * 1152 + col];
    }

    float accq = 0.0f, acc0 = 0.0f, acc1 = 0.0f, acc2 = 0.0f;
    int p0 = rowptr[ia], p1 = rowptr[ia + 1];
    int p = p0;
    for (; p + 4 <= p1; p += 4) {
        int jj[4]; float4 df[4];
        #pragma unroll
        for (int e = 0; e < 4; e++) { jj[e] = j_s[p + e]; df[e] = df_s[p + e]; }
        float dots[4][3];
        #pragma unroll
        for (int e = 0; e < 4; e++)
            #pragma unroll
            for (int c = 0; c < 3; c++) dots[e][c] = df[e].w * b3[c];
        #pragma unroll
        for (int kq = 0; kq < 5; kq++) {
            float4 a[4];
            #pragma unroll
            for (int e = 0; e < 4; e++)
                a[e] = *(const float4*)(phi_s + (size_t)(p + e) * 20 + kq * 4);
            #pragma unroll
            for (int e = 0; e < 4; e++) {
                #pragma unroll
                for (int c = 0; c < 3; c++) {
                    dots[e][c] = fmaf(a[e].x, wreg[c][kq*4+0], dots[e][c]);
                    dots[e][c] = fmaf(a[e].y, wreg[c][kq*4+1], dots[e][c]);
                    dots[e][c] = fmaf(a[e].z, wreg[c][kq*4+2], dots[e][c]);
                    dots[e][c] = fmaf(a[e].w, wreg[c][kq*4+3], dots[e][c]);
                }
            }
        }
        float xv[4][3], mv[4][3];
        #pragma unroll
        for (int e = 0; e < 4; e++) {
            size_t xb = (size_t)jj[e] * 384;
            xv[e][0] = x[xb + h*64 + lane];
            xv[e][1] = x[xb + (2+h)*64 + lane];
            xv[e][2] = x[xb + (4+h)*64 + lane];
            #pragma unroll
            for (int d = 0; d < 3; d++)
                mv[e][d] = mu_in[((size_t)jj[e]*3 + d)*128 + f];
        }
        #pragma unroll
        for (int e = 0; e < 4; e++) {
            float xxq = dots[e][0] * xv[e][0];
            float xxr = dots[e][1] * xv[e][1];
            float xxm = dots[e][2] * xv[e][2];
            accq += xxq;
            acc0 += xxr * df[e].x + xxm * mv[e][0];
            acc1 += xxr * df[e].y + xxm * mv[e][1];
            acc2 += xxr * df[e].z + xxm * mv[e][2];
        }
    }
    for (; p < p1; p++) {
        int j0 = j_s[p];
        float4 d0 = df_s[p];
        float dots0[3];
        #pragma unroll
        for (int c = 0; c < 3; c++) dots0[c] = d0.w * b3[c];
        #pragma unroll
        for (int kq = 0; kq < 5; kq++) {
            float4 a0 = *(const float4*)(phi_s + (size_t)p * 20 + kq * 4);
            #pragma unroll
            for (int c = 0; c < 3; c++) {
                dots0[c] = fmaf(a0.x, wreg[c][kq*4+0], dots0[c]);
                dots0[c] = fmaf(a0.y, wreg[c][kq*4+1], dots0[c]);
                dots0[c] = fmaf(a0.z, wreg[c][kq*4+2], dots0[c]);
                dots0[c] = fmaf(a0.w, wreg[c][kq*4+3], dots0[c]);
            }
        }
        size_t xb = (size_t)j0 * 384;
        float xq0 = x[xb + h*64 + lane];
        float xr0 = x[xb + (2+h)*64 + lane];
        float xm0 = x[xb + (4+h)*64 + lane];
        float m00 = mu_in[((size_t)j0*3 + 0)*128 + f];
        float m01 = mu_in[((size_t)j0*3 + 1)*128 + f];
        float m02 = mu_in[((size_t)j0*3 + 2)*128 + f];
        float xxq0 = dots0[0] * xq0, xxr0 = dots0[1] * xr0, xxm0 = dots0[2] * xm0;
        accq += xxq0;
        acc0 += xxr0*d0.x + xxm0*m00;
        acc1 += xxr0*d0.y + xxm0*m01;
        acc2 += xxr0*d0.z + xxm0*m02;
    }
    q[(size_t)ia*128 + f] += accq;
    mu_out[((size_t)ia*3 + 0)*128 + f] = mu_in[((size_t)ia*3 + 0)*128 + f] + acc0;
    mu_out[((size_t)ia*3 + 1)*128 + f] = mu_in[((size_t)ia*3 + 1)*128 + f] + acc1;
    mu_out[((size_t)ia*3 + 2)*128 + f] = mu_in[((size_t)ia*3 + 2)*128 + f] + acc2;
}

// ---------------- field interaction elementwise update -------------------------
__global__ __launch_bounds__(256) void k_field(
    const float* __restrict__ a_s, const float* __restrict__ av,
    const float* __restrict__ Eat, float* __restrict__ mu)
{
    int gid = blockIdx.x * 256 + threadIdx.x;
    if (gid >= NA * 128) return;
    int i = gid >> 7, f = gid & 127;
    float E0 = Eat[i*3+0], E1 = Eat[i*3+1], E2 = Eat[i*3+2];
    float a0 = av[(i*3+0)*128+f], a1 = av[(i*3+1)*128+f], a2 = av[(i*3+2)*128+f];
    float dot = a0*E0 + a1*E1 + a2*E2;
    float s = a_s[gid];
    mu[(i*3+0)*128+f] += s*E0 - dot*a0;
    mu[(i*3+1)*128+f] += s*E1 - dot*a1;
    mu[(i*3+2)*128+f] += s*E2 - dot*a2;
}

// ---------------- mixing: mu_Vn and ctx = [q, mu_Vn] ---------------------------
__global__ __launch_bounds__(256) void k_mixnorm(
    const float* __restrict__ q, const float* __restrict__ mumix,
    float* __restrict__ ctx)
{
    int gid = blockIdx.x * 256 + threadIdx.x;
    if (gid >= NA * 128) return;
    int i = gid >> 7, f = gid & 127;
    float v0 = mumix[(i*3+0)*256+f], v1 = mumix[(i*3+1)*256+f], v2 = mumix[(i*3+2)*256+f];
    float vn = sqrtf(v0*v0 + v1*v1 + v2*v2 + 1e-8f);
    ctx[i*256 + f]       = q[gid];
    ctx[i*256 + 128 + f] = vn;
}

// ---------------- mixing final update ------------------------------------------
__global__ __launch_bounds__(256) void k_mixupd(
    const float* __restrict__ y, const float* __restrict__ mumix,
    float* __restrict__ q, float* __restrict__ mu)
{
    int gid = blockIdx.x * 256 + threadIdx.x;
    if (gid >= NA * 128) return;
    int i = gid >> 7, f = gid & 127;
    float yq  = y[i*384 + f];
    float ym  = y[i*384 + 128 + f];
    float yqm = y[i*384 + 256 + f];
    float sdot = 0.f;
    #pragma unroll
    for (int d = 0; d < 3; d++)
        sdot += mumix[(i*3+d)*256 + f] * mumix[(i*3+d)*256 + 128 + f];
    q[gid] += yq + yqm * sdot;
    #pragma unroll
    for (int d = 0; d < 3; d++)
        mu[(i*3+d)*128 + f] += ym * mumix[(i*3+d)*256 + 128 + f];
}

// ---------------- pack output [N,4,128] = [q, mu] -------------------------------
__global__ __launch_bounds__(256) void k_pack(
    const float* __restrict__ q, const float* __restrict__ mu,
    float* __restrict__ out)
{
    int gid = blockIdx.x * 256 + threadIdx.x;
    if (gid >= NA * 512) return;
    int i = gid >> 9, c = gid & 511;
    out[gid] = (c < 128) ? q[i*128 + c] : mu[i*384 + (c - 128)];
}

extern "C" void kernel_launch(void* const* d_in, const int* in_sizes, int n_in,
                              void* d_out, int out_size, void* d_ws, size_t ws_size,
                              hipStream_t stream)
{
    const int*   Z       = (const int*)d_in[0];
    const float* r_ij    = (const float*)d_in[1];
    const int*   idx_i   = (const int*)d_in[2];
    const int*   idx_j   = (const int*)d_in[3];
    const int*   idx_m   = (const int*)d_in[4];
    const float* e_field = (const float*)d_in[5];
    const float* emb     = (const float*)d_in[6];
    const float* filt_W  = (const float*)d_in[7];
    const float* filt_b  = (const float*)d_in[8];
    const float* iW1     = (const float*)d_in[9];
    const float* ib1     = (const float*)d_in[10];
    const float* iW2     = (const float*)d_in[11];
    const float* ib2     = (const float*)d_in[12];
    const float* sW1     = (const float*)d_in[13];
    const float* sb1     = (const float*)d_in[14];
    const float* sW2     = (const float*)d_in[15];
    const float* sb2     = (const float*)d_in[16];
    const float* vW      = (const float*)d_in[17];
    const float* mmW     = (const float*)d_in[18];
    const float* mW1     = (const float*)d_in[19];
    const float* mb1     = (const float*)d_in[20];
    const float* mW2     = (const float*)d_in[21];
    const float* mb2     = (const float*)d_in[22];
    float* out = (float*)d_out;

    float* base = (float*)d_ws;
    size_t off = 0;
    auto alloc = [&](size_t n) { float* p = base + off; off += (n + 255) & ~(size_t)255; return p; };
    float* q     = alloc((size_t)NA*128);
    float* mu_a  = alloc((size_t)NA*384);
    float* mu_b  = alloc((size_t)NA*384);
    float* h     = alloc((size_t)NA*128);
    float* a_s   = alloc((size_t)NA*128);
    float* s384  = alloc((size_t)NA*384);
    float* mumix = alloc((size_t)NA*768);
    float* ctx   = alloc((size_t)NA*256);
    float* Eat   = alloc((size_t)NA*3);
    float* phi_s = alloc((size_t)NE*20);
    float4* df_s = (float4*)alloc((size_t)NE*4);
    int* rowptr  = (int*)alloc(NA + 1);
    int* counts  = (int*)alloc(NA);
    int* cursor  = (int*)alloc(NA);
    int* j_s     = (int*)alloc(NE);
    unsigned short* wth = (unsigned short*)alloc(344064 + 256);
    unsigned short* wtl = (unsigned short*)alloc(344064 + 256);
    (void)ws_size; (void)in_sizes; (void)n_in; (void)out_size;

    // --- weight prep descriptors (per t: iW1,iW2,sW1,sW2,vW,mmW,mW1,mW2) -------
    WPack P;
    size_t woff = 0;
    unsigned short* WH[3][8];
    unsigned short* WL[3][8];
    int nw = 0;
    auto reg = [&](const float* src, int K, int N, int t, int slot) {
        P.w[nw].src = src; P.w[nw].dh = wth + woff; P.w[nw].dl = wtl + woff;
        P.w[nw].K = K; P.w[nw].N = N;
        WH[t][slot] = wth + woff; WL[t][slot] = wtl + woff;
        woff += (size_t)K * N; nw++;
    };
    for (int t = 0; t < 3; t++) {
        reg(iW1 + t*128*128, 128, 128, t, 0);
        reg(iW2 + t*128*384, 128, 384, t, 1);
        reg(sW1 + t*128*128, 128, 128, t, 2);
        reg(sW2 + t*128*128, 128, 128, t, 3);
        reg(vW  + t*128*128, 128, 128, t, 4);
        reg(mmW + t*128*256, 128, 256, t, 5);
        reg(mW1 + t*256*128, 256, 128, t, 6);
        reg(mW2 + t*128*384, 128, 384, t, 7);
    }

    k_wprep       <<<dim3(24, 24),          256, 0, stream>>>(P);
    k_init        <<<(NA*384 + 255)/256,    256, 0, stream>>>(Z, idx_m, emb, e_field, q, mu_a, Eat, counts, cursor);
    k_count       <<<(NE + 255)/256,        256, 0, stream>>>(idx_i, counts);
    k_scan        <<<1,                     256, 0, stream>>>(counts, rowptr);
    k_geom_scatter<<<(NE + 255)/256,        256, 0, stream>>>(r_ij, idx_i, idx_j, rowptr, cursor,
                                                              phi_s, df_s, j_s);

    const int G64  = (NA + 63) / 64;        // 157
    const int G64x3 = (NA*3 + 63) / 64;     // 469
    float* mu_cur = mu_a;
    float* mu_nxt = mu_b;
    for (int t = 0; t < 3; t++) {
        // Interaction MLP: x = silu(q@iW1+b1)@iW2+b2
        k_gmm2<1><<<dim3(G64, 2),   256, 0, stream>>>(q, WH[t][0], WL[t][0], ib1 + t*128, h,    NA, 128, 128);
        k_gmm2<0><<<dim3(G64, 6),   256, 0, stream>>>(h, WH[t][1], WL[t][1], ib2 + t*384, s384, NA, 128, 384);
        // edge message passing (owner-exclusive, no atomics)
        k_edge4<<<NA/2, 256, 0, stream>>>(t, phi_s, df_s, j_s, rowptr, s384,
                                          mu_cur, filt_W, filt_b, q, mu_nxt);
        { float* tmp = mu_cur; mu_cur = mu_nxt; mu_nxt = tmp; }
        // FieldInteraction
        k_gmm2<1><<<dim3(G64, 2),   256, 0, stream>>>(q,      WH[t][2], WL[t][2], sb1 + t*128, h,    NA,   128, 128);
        k_gmm2<0><<<dim3(G64, 2),   256, 0, stream>>>(h,      WH[t][3], WL[t][3], sb2 + t*128, a_s,  NA,   128, 128);
        k_gmm2<0><<<dim3(G64x3, 2), 256, 0, stream>>>(mu_cur, WH[t][4], WL[t][4], nullptr,     s384, NA*3, 128, 128);
        k_field<<<(NA*128 + 255)/256, 256, 0, stream>>>(a_s, s384, Eat, mu_cur);
        // Mixing
        k_gmm2<0><<<dim3(G64x3, 4), 256, 0, stream>>>(mu_cur, WH[t][5], WL[t][5], nullptr,     mumix, NA*3, 128, 256);
        k_mixnorm<<<(NA*128 + 255)/256, 256, 0, stream>>>(q, mumix, ctx);
        k_gmm2<1><<<dim3(G64, 2),   256, 0, stream>>>(ctx,    WH[t][6], WL[t][6], mb1 + t*128, h,    NA, 256, 128);
        k_gmm2<0><<<dim3(G64, 6),   256, 0, stream>>>(h,      WH[t][7], WL[t][7], mb2 + t*384, s384, NA, 128, 384);
        k_mixupd<<<(NA*128 + 255)/256, 256, 0, stream>>>(s384, mumix, q, mu_cur);
    }
    k_pack<<<(NA*512 + 255)/256, 256, 0, stream>>>(q, mu_cur, out);
}